// Round 1
// baseline (175.250 us; speedup 1.0000x reference)
//
#include <hip/hip_runtime.h>
#include <stdint.h>
#include <stddef.h>

#define BDIM 4
#define QUE  128
#define VAL  128
#define DD   512
#define BQ   (BDIM*QUE)
#define BK   32
#define APAD 40   // padded LDS row stride (fp16 elems): 80B rows -> conflict-free b128

typedef float    f32x4 __attribute__((ext_vector_type(4)));
typedef _Float16 f16x8 __attribute__((ext_vector_type(8)));

// ---------------- W1 transpose + fp16 cast (runs every launch; W1 reused 512x) ----
__global__ __launch_bounds__(256) void w1t_kernel(const float* __restrict__ W1,
                                                  _Float16* __restrict__ W1T) {
    __shared__ float tile[32][33];
    int tx = threadIdx.x & 31;
    int ty = threadIdx.x >> 5;            // 0..7
    int d0 = blockIdx.x * 32;
    int e0 = blockIdx.y * 32;
    #pragma unroll
    for (int r = 0; r < 4; ++r)
        tile[ty + r*8][tx] = W1[(size_t)(d0 + ty + r*8) * DD + e0 + tx];
    __syncthreads();
    #pragma unroll
    for (int r = 0; r < 4; ++r) {
        int el = ty + r*8;
        W1T[(size_t)(e0 + el) * DD + d0 + tx] = (_Float16)tile[tx][el];
    }
}

// ---------------- fused GEMM: h=relu((q*k)@W1+b1); emit s-partials + masked colsums
// grid: (BQ, 4 e-tiles), block 256 (4 waves, 2x2 of 64x64; each wave 4x4 MFMA tiles)
__global__ __launch_bounds__(256, 2) void gemm_h_kernel(
    const float* __restrict__ qs1,
    const float* __restrict__ ks,
    const int*   __restrict__ sgmask,
    const _Float16* __restrict__ W1T,   // [e][d] fp16
    const float* __restrict__ b1,
    const float* __restrict__ W2,
    float* __restrict__ s_part,         // [BQ][4][VAL]
    float* __restrict__ meansum)        // [BQ][DD]
{
    __shared__ _Float16 Ah[VAL * APAD];   // x tile   [v][k]
    __shared__ _Float16 Bh[128 * APAD];   // W1T tile [e][k]
    __shared__ float qrow[DD];
    __shared__ float sred[2][VAL];
    __shared__ float msumLDS[2][128];

    const int tid  = threadIdx.x;
    const int bq   = blockIdx.x;
    const int et   = blockIdx.y;
    const int b    = bq >> 7;
    const int lane = tid & 63;
    const int wid  = tid >> 6;
    const int wm   = wid >> 1, wn = wid & 1;
    const int quad = lane >> 4;
    const int lr   = lane & 15;

    if (tid < 128) {
        *(f32x4*)(qrow + tid * 4) = *(const f32x4*)(qs1 + (size_t)bq * DD + tid * 4);
    }
    __syncthreads();

    f32x4 acc[4][4];
    #pragma unroll
    for (int i = 0; i < 4; ++i)
        #pragma unroll
        for (int j = 0; j < 4; ++j) acc[i][j] = (f32x4){0.f, 0.f, 0.f, 0.f};

    const int vrow  = tid >> 1;          // doubles as A-row (v) and B-row (e local)
    const int dbase = (tid & 1) * 16;
    const float*    ksrow  = ks  + ((size_t)b * VAL + vrow) * DD;
    const _Float16* w1trow = W1T + (size_t)(et * 128 + vrow) * DD;

    for (int kk = 0; kk < DD; kk += BK) {
        // ---- stage A: x = q*k, fp32->fp16 (RNE), padded LDS
        f16x8 a0, a1;
        #pragma unroll
        for (int j = 0; j < 2; ++j) {
            f32x4 kv0 = *(const f32x4*)(ksrow + kk + dbase + j*8);
            f32x4 kv1 = *(const f32x4*)(ksrow + kk + dbase + j*8 + 4);
            f32x4 qv0 = *(const f32x4*)(qrow  + kk + dbase + j*8);
            f32x4 qv1 = *(const f32x4*)(qrow  + kk + dbase + j*8 + 4);
            f16x8* dst = j ? &a1 : &a0;
            #pragma unroll
            for (int c = 0; c < 4; ++c) {
                (*dst)[c]     = (_Float16)(kv0[c] * qv0[c]);
                (*dst)[c + 4] = (_Float16)(kv1[c] * qv1[c]);
            }
        }
        *(f16x8*)(&Ah[vrow * APAD + dbase])     = a0;
        *(f16x8*)(&Ah[vrow * APAD + dbase + 8]) = a1;
        // ---- stage B: straight fp16 copy of W1T tile
        f16x8 b0 = *(const f16x8*)(w1trow + kk + dbase);
        f16x8 b1v_ = *(const f16x8*)(w1trow + kk + dbase + 8);
        *(f16x8*)(&Bh[vrow * APAD + dbase])     = b0;
        *(f16x8*)(&Bh[vrow * APAD + dbase + 8]) = b1v_;
        __syncthreads();

        // ---- MFMA: A[m=lr][k=quad*8+j], B[k=quad*8+j][n=lr]
        f16x8 fa[4], fb[4];
        #pragma unroll
        for (int mt = 0; mt < 4; ++mt)
            fa[mt] = *(const f16x8*)(&Ah[(wm*64 + mt*16 + lr) * APAD + quad*8]);
        #pragma unroll
        for (int nt = 0; nt < 4; ++nt)
            fb[nt] = *(const f16x8*)(&Bh[(wn*64 + nt*16 + lr) * APAD + quad*8]);
        #pragma unroll
        for (int mt = 0; mt < 4; ++mt)
            #pragma unroll
            for (int nt = 0; nt < 4; ++nt)
                acc[mt][nt] = __builtin_amdgcn_mfma_f32_16x16x32_f16(fa[mt], fb[nt], acc[mt][nt], 0, 0, 0);
        __syncthreads();
    }

    // ---- fused epilogue: C/D layout col=lr, row=quad*4+reg
    float b1v[4], w2v[4];
    #pragma unroll
    for (int nt = 0; nt < 4; ++nt) {
        int col = et*128 + wn*64 + nt*16 + lr;
        b1v[nt] = b1[col];
        w2v[nt] = W2[col];
    }
    float msum[4] = {0.f, 0.f, 0.f, 0.f};
    #pragma unroll
    for (int mt = 0; mt < 4; ++mt) {
        #pragma unroll
        for (int reg = 0; reg < 4; ++reg) {
            int v = wm*64 + mt*16 + quad*4 + reg;
            int masked = sgmask[b * VAL + v];
            float sacc = 0.f;
            #pragma unroll
            for (int nt = 0; nt < 4; ++nt) {
                float h = acc[mt][nt][reg] + b1v[nt];
                h = fmaxf(h, 0.f);
                sacc += h * w2v[nt];
                if (!masked) msum[nt] += h;
            }
            sacc += __shfl_xor(sacc, 1);
            sacc += __shfl_xor(sacc, 2);
            sacc += __shfl_xor(sacc, 4);
            sacc += __shfl_xor(sacc, 8);
            if (lr == 0) sred[wn][v] = sacc;
        }
    }
    #pragma unroll
    for (int nt = 0; nt < 4; ++nt) {
        float m = msum[nt];
        m += __shfl_xor(m, 16);
        m += __shfl_xor(m, 32);
        if (lane < 16) msumLDS[wm][wn*64 + nt*16 + lr] = m;
    }
    __syncthreads();
    if (tid < 128) {
        s_part[((size_t)bq * 4 + et) * VAL + tid] = sred[0][tid] + sred[1][tid];
        meansum[(size_t)bq * DD + et*128 + tid]   = msumLDS[0][tid] + msumLDS[1][tid];
    }
}

// ---------------- finish: softmax, mean/gate, weighted sum of vs ----------------
__global__ __launch_bounds__(256) void finish_kernel(
    const float* __restrict__ s_part,
    const float* __restrict__ meansum,
    const int*   __restrict__ sgmask,
    const float* __restrict__ vs,
    const float* __restrict__ Wse,
    const float* __restrict__ bse,
    const float* __restrict__ b2,
    float* __restrict__ out)
{
    __shared__ float wexp[VAL];
    __shared__ float meanLDS[DD];
    __shared__ float red[2];   // [0]=1/sum_exp, [1]=1/denom
    const int tid = threadIdx.x;
    const int bq  = blockIdx.x;
    const int b   = bq >> 7;

    if (tid < 64) {  // wave 0: softmax over 128 v (2 per lane) + denom count
        int v0 = tid, v1 = tid + 64;
        const float* sp = s_part + (size_t)bq * 4 * VAL;
        float s0 = sp[v0] + sp[VAL + v0] + sp[2*VAL + v0] + sp[3*VAL + v0] + b2[0];
        float s1 = sp[v1] + sp[VAL + v1] + sp[2*VAL + v1] + sp[3*VAL + v1] + b2[0];
        s0 = fmaxf(s0, 0.f);  s1 = fmaxf(s1, 0.f);
        int m0 = sgmask[b * VAL + v0], m1 = sgmask[b * VAL + v1];
        float cnt = (m0 ? 0.f : 1.f) + (m1 ? 0.f : 1.f);
        if (m0) s0 = -1e9f;
        if (m1) s1 = -1e9f;
        float mx = fmaxf(s0, s1);
        #pragma unroll
        for (int off = 32; off; off >>= 1) mx = fmaxf(mx, __shfl_xor(mx, off));
        float e0 = __expf(s0 - mx), e1 = __expf(s1 - mx);
        float se = e0 + e1;
        #pragma unroll
        for (int off = 32; off; off >>= 1) {
            se  += __shfl_xor(se, off);
            cnt += __shfl_xor(cnt, off);
        }
        wexp[v0] = e0;  wexp[v1] = e1;
        if (tid == 0) { red[0] = 1.f / se; red[1] = 1.f / cnt; }
    }
    __syncthreads();
    const float invd = red[1];
    meanLDS[tid]       = meansum[(size_t)bq * DD + tid]       * invd;
    meanLDS[tid + 256] = meansum[(size_t)bq * DD + tid + 256] * invd;
    __syncthreads();
    const float invse = red[0];
    #pragma unroll
    for (int half = 0; half < 2; ++half) {
        int d = tid + half * 256;
        float g = bse[d];
        for (int e = 0; e < DD; ++e) g += meanLDS[e] * Wse[(size_t)e * DD + d];
        g = fmaxf(g, 0.f);
        g = 1.f / (1.f + __expf(-g));           // sigmoid(relu(.))
        float o = 0.f;
        const float* vsb = vs + (size_t)b * VAL * DD + d;
        for (int v = 0; v < VAL; ++v) o += wexp[v] * vsb[(size_t)v * DD];
        out[(size_t)bq * DD + d] = g * o * invse;
    }
}

extern "C" void kernel_launch(void* const* d_in, const int* in_sizes, int n_in,
                              void* d_out, int out_size, void* d_ws, size_t ws_size,
                              hipStream_t stream) {
    (void)in_sizes; (void)n_in; (void)out_size; (void)ws_size;
    const float* qs1 = (const float*)d_in[0];
    // d_in[1] (qs_2) is unused by the reference
    const float* ks  = (const float*)d_in[2];
    const float* vs  = (const float*)d_in[3];
    const int*   sg  = (const int*)d_in[4];
    const float* W1  = (const float*)d_in[5];
    const float* b1  = (const float*)d_in[6];
    const float* Wse = (const float*)d_in[7];
    const float* bse = (const float*)d_in[8];
    const float* W2  = (const float*)d_in[9];
    const float* b2  = (const float*)d_in[10];
    float* out = (float*)d_out;

    char* ws = (char*)d_ws;
    _Float16* W1T    = (_Float16*)ws;                      // 512 KB
    float*    s_part = (float*)(ws + (512 << 10));         // 512*4*128*4 = 1 MB
    float*    msum   = (float*)(ws + (512 << 10) + (1 << 20)); // 1 MB

    w1t_kernel<<<dim3(16, 16), 256, 0, stream>>>(W1, W1T);
    gemm_h_kernel<<<dim3(BQ, 4), 256, 0, stream>>>(qs1, ks, sg, W1T, b1, W2, s_part, msum);
    finish_kernel<<<BQ, 256, 0, stream>>>(s_part, msum, sg, vs, Wse, bse, b2, out);
}

// Round 2
// 161.188 us; speedup vs baseline: 1.0872x; 1.0872x over previous
//
#include <hip/hip_runtime.h>
#include <stdint.h>
#include <stddef.h>

#define BDIM 4
#define QUE  128
#define VAL  128
#define DD   512
#define BQ   (BDIM*QUE)
#define BK   32
#define APAD 40   // padded LDS row stride (fp16): 80B rows, conflict-free b128 frag reads

typedef float    f32x4 __attribute__((ext_vector_type(4)));
typedef _Float16 f16x8 __attribute__((ext_vector_type(8)));
typedef _Float16 f16x4 __attribute__((ext_vector_type(4)));

// ---------------- prep: W1 transpose+cast to fp16 [e][d]; Wse cast to fp16 -------
__global__ __launch_bounds__(256) void prep_kernel(const float* __restrict__ W1,
                                                   _Float16* __restrict__ W1T,
                                                   const float* __restrict__ Wse,
                                                   _Float16* __restrict__ WseH) {
    if (blockIdx.y < 16) {
        __shared__ float tile[32][33];
        int tx = threadIdx.x & 31;
        int ty = threadIdx.x >> 5;            // 0..7
        int d0 = blockIdx.x * 32;
        int e0 = blockIdx.y * 32;
        #pragma unroll
        for (int r = 0; r < 4; ++r)
            tile[ty + r*8][tx] = W1[(size_t)(d0 + ty + r*8) * DD + e0 + tx];
        __syncthreads();
        #pragma unroll
        for (int r = 0; r < 4; ++r) {
            int el = ty + r*8;
            W1T[(size_t)(e0 + el) * DD + d0 + tx] = (_Float16)tile[tx][el];
        }
    } else if (blockIdx.x < 2) {
        // cast Wse (262144 floats) -> fp16, 2 blocks x 256 threads x 512 elems
        size_t base = (size_t)blockIdx.x * 131072 + threadIdx.x * 4;
        for (int i = 0; i < 128; ++i) {
            f32x4 w = *(const f32x4*)(Wse + base + (size_t)i * 1024);
            f16x4 h;
            h[0] = (_Float16)w[0]; h[1] = (_Float16)w[1];
            h[2] = (_Float16)w[2]; h[3] = (_Float16)w[3];
            *(f16x4*)(WseH + base + (size_t)i * 1024) = h;
        }
    }
}

// ---------------- fused GEMM: h=relu((q*k)@W1+b1); emit s-partials + masked colsums
// grid (BQ, 2); block 512 = 8 waves as 2m x 4n of 64x64. Tile 128 rows x 256 e-cols.
__global__ __launch_bounds__(512, 4) void gemm_h_kernel(
    const float* __restrict__ qs1,
    const float* __restrict__ ks,
    const int*   __restrict__ sgmask,
    const _Float16* __restrict__ W1T,   // [e][d] fp16
    const float* __restrict__ b1,
    const float* __restrict__ W2,
    float* __restrict__ s_part,         // [BQ][2][VAL]
    float* __restrict__ meansum)        // [BQ][DD]
{
    __shared__ _Float16 Ah[VAL * APAD];   // x tile   [v][k]   128 rows
    __shared__ _Float16 Bh[256 * APAD];   // W1T tile [e][k]   256 rows
    __shared__ float qrow[DD];
    __shared__ float sred[4][VAL];
    __shared__ float msumLDS[2][256];

    const int tid  = threadIdx.x;
    const int bq   = blockIdx.x;
    const int gy   = blockIdx.y;          // e-half: cols [gy*256, gy*256+256)
    const int b    = bq >> 7;
    const int lane = tid & 63;
    const int wid  = tid >> 6;            // 0..7
    const int wm   = wid >> 2;            // 0..1 (rows wm*64)
    const int wn   = wid & 3;             // 0..3 (cols wn*64)
    const int quad = lane >> 4;
    const int lr   = lane & 15;

    if (tid < 128)
        *(f32x4*)(qrow + tid * 4) = *(const f32x4*)(qs1 + (size_t)bq * DD + tid * 4);
    __syncthreads();

    f32x4 acc[4][4];
    #pragma unroll
    for (int i = 0; i < 4; ++i)
        #pragma unroll
        for (int j = 0; j < 4; ++j) acc[i][j] = (f32x4){0.f, 0.f, 0.f, 0.f};

    // A staging: thread -> (row=tid>>2 of 128, 8-k segment), B: (row=tid>>1 of 256, 16-k half)
    const int arow = tid >> 2,  adb = (tid & 3) * 8;
    const int erow = tid >> 1,  bdb = (tid & 1) * 16;
    const float*    ksrow  = ks  + ((size_t)b * VAL + arow) * DD;
    const _Float16* w1trow = W1T + (size_t)(gy * 256 + erow) * DD;

    for (int kk = 0; kk < DD; kk += BK) {
        // ---- stage A: x = q*k, fp32->fp16 RNE (8 f16/thread)
        f32x4 kv0 = *(const f32x4*)(ksrow + kk + adb);
        f32x4 kv1 = *(const f32x4*)(ksrow + kk + adb + 4);
        f32x4 qv0 = *(const f32x4*)(qrow  + kk + adb);
        f32x4 qv1 = *(const f32x4*)(qrow  + kk + adb + 4);
        f16x8 av;
        #pragma unroll
        for (int c = 0; c < 4; ++c) {
            av[c]     = (_Float16)(kv0[c] * qv0[c]);
            av[c + 4] = (_Float16)(kv1[c] * qv1[c]);
        }
        *(f16x8*)(&Ah[arow * APAD + adb]) = av;
        // ---- stage B: fp16 copy (16 f16/thread)
        f16x8 bv0 = *(const f16x8*)(w1trow + kk + bdb);
        f16x8 bv1 = *(const f16x8*)(w1trow + kk + bdb + 8);
        *(f16x8*)(&Bh[erow * APAD + bdb])     = bv0;
        *(f16x8*)(&Bh[erow * APAD + bdb + 8]) = bv1;
        __syncthreads();

        // ---- MFMA: A[m=lr][k=quad*8+j], B[k=quad*8+j][n=lr]
        f16x8 fa[4];
        #pragma unroll
        for (int mt = 0; mt < 4; ++mt)
            fa[mt] = *(const f16x8*)(&Ah[(wm*64 + mt*16 + lr) * APAD + quad*8]);
        #pragma unroll
        for (int nt = 0; nt < 4; ++nt) {
            f16x8 fb = *(const f16x8*)(&Bh[(wn*64 + nt*16 + lr) * APAD + quad*8]);
            #pragma unroll
            for (int mt = 0; mt < 4; ++mt)
                acc[mt][nt] = __builtin_amdgcn_mfma_f32_16x16x32_f16(fa[mt], fb, acc[mt][nt], 0, 0, 0);
        }
        __syncthreads();
    }

    // ---- fused epilogue: C/D layout col=lr (e), row=quad*4+reg (v)
    float b1v[4], w2v[4];
    #pragma unroll
    for (int nt = 0; nt < 4; ++nt) {
        int col = gy*256 + wn*64 + nt*16 + lr;
        b1v[nt] = b1[col];
        w2v[nt] = W2[col];
    }
    float msum[4] = {0.f, 0.f, 0.f, 0.f};
    #pragma unroll
    for (int mt = 0; mt < 4; ++mt) {
        #pragma unroll
        for (int reg = 0; reg < 4; ++reg) {
            int v = wm*64 + mt*16 + quad*4 + reg;
            int masked = sgmask[b * VAL + v];
            float sacc = 0.f;
            #pragma unroll
            for (int nt = 0; nt < 4; ++nt) {
                float h = acc[mt][nt][reg] + b1v[nt];
                h = fmaxf(h, 0.f);
                sacc += h * w2v[nt];
                if (!masked) msum[nt] += h;
            }
            sacc += __shfl_xor(sacc, 1);
            sacc += __shfl_xor(sacc, 2);
            sacc += __shfl_xor(sacc, 4);
            sacc += __shfl_xor(sacc, 8);
            if (lr == 0) sred[wn][v] = sacc;
        }
    }
    #pragma unroll
    for (int nt = 0; nt < 4; ++nt) {
        float m = msum[nt];
        m += __shfl_xor(m, 16);
        m += __shfl_xor(m, 32);
        if (lane < 16) msumLDS[wm][wn*64 + nt*16 + lr] = m;
    }
    __syncthreads();
    if (tid < 128) {
        s_part[((size_t)bq * 2 + gy) * VAL + tid] =
            sred[0][tid] + sred[1][tid] + sred[2][tid] + sred[3][tid];
    } else if (tid >= 256) {
        int c = tid - 256;
        meansum[(size_t)bq * DD + gy*256 + c] = msumLDS[0][c] + msumLDS[1][c];
    }
}

// ---------------- finish: softmax, gate, weighted sum — grid (BQ, 4 d-tiles) ------
__global__ __launch_bounds__(256) void finish_kernel(
    const float* __restrict__ s_part,     // [BQ][2][VAL]
    const float* __restrict__ meansum,    // [BQ][DD] (un-normalized)
    const int*   __restrict__ sgmask,
    const float* __restrict__ vs,
    const _Float16* __restrict__ WseH,    // [e][d] fp16
    const float* __restrict__ bse,
    const float* __restrict__ b2,
    float* __restrict__ out)
{
    __shared__ float wexp[VAL];
    __shared__ float meanLDS[DD];         // raw colsums (invd deferred — linear)
    __shared__ float gred[2][128];
    __shared__ float ored[2][128];
    __shared__ float redv[2];             // [0]=1/sum_exp  [1]=1/denom
    const int tid = threadIdx.x;
    const int bq  = blockIdx.x;
    const int dt  = blockIdx.y;
    const int b   = bq >> 7;

    meanLDS[tid]       = meansum[(size_t)bq * DD + tid];
    meanLDS[tid + 256] = meansum[(size_t)bq * DD + tid + 256];

    if (tid < 64) {   // wave 0: softmax over 128 v (2/lane) + denom count
        int v0 = tid, v1 = tid + 64;
        const float* sp = s_part + (size_t)bq * 2 * VAL;
        float s0 = fmaxf(sp[v0] + sp[VAL + v0] + b2[0], 0.f);
        float s1 = fmaxf(sp[v1] + sp[VAL + v1] + b2[0], 0.f);
        int m0 = sgmask[b * VAL + v0], m1 = sgmask[b * VAL + v1];
        float cnt = (m0 ? 0.f : 1.f) + (m1 ? 0.f : 1.f);
        if (m0) s0 = -1e9f;
        if (m1) s1 = -1e9f;
        float mx = fmaxf(s0, s1);
        #pragma unroll
        for (int off = 32; off; off >>= 1) mx = fmaxf(mx, __shfl_xor(mx, off));
        float e0 = __expf(s0 - mx), e1 = __expf(s1 - mx);
        float se = e0 + e1;
        #pragma unroll
        for (int off = 32; off; off >>= 1) {
            se  += __shfl_xor(se, off);
            cnt += __shfl_xor(cnt, off);
        }
        wexp[v0] = e0;  wexp[v1] = e1;
        if (tid == 0) { redv[0] = 1.f / se; redv[1] = 1.f / cnt; }
    }
    __syncthreads();

    const int dl = tid & 127;
    const int d  = dt * 128 + dl;
    const int half = tid >> 7;            // splits the serial loops across thread halves

    float g = 0.f;
    const _Float16* wp = WseH + (size_t)(half * 256) * DD + d;
    const float*    mp = meanLDS + half * 256;
    #pragma unroll 8
    for (int e = 0; e < 256; ++e) g += mp[e] * (float)wp[(size_t)e * DD];
    gred[half][dl] = g;

    float o = 0.f;
    const float* vp = vs + ((size_t)b * VAL + half * 64) * DD + d;
    const float* wx = wexp + half * 64;
    #pragma unroll 8
    for (int v = 0; v < 64; ++v) o += wx[v] * vp[(size_t)v * DD];
    ored[half][dl] = o;
    __syncthreads();

    if (tid < 128) {
        float gate = (gred[0][tid] + gred[1][tid]) * redv[1] + bse[d];
        gate = fmaxf(gate, 0.f);
        gate = 1.f / (1.f + __expf(-gate));
        out[(size_t)bq * DD + d] = gate * (ored[0][tid] + ored[1][tid]) * redv[0];
    }
}

extern "C" void kernel_launch(void* const* d_in, const int* in_sizes, int n_in,
                              void* d_out, int out_size, void* d_ws, size_t ws_size,
                              hipStream_t stream) {
    (void)in_sizes; (void)n_in; (void)out_size; (void)ws_size;
    const float* qs1 = (const float*)d_in[0];
    const float* ks  = (const float*)d_in[2];
    const float* vs  = (const float*)d_in[3];
    const int*   sg  = (const int*)d_in[4];
    const float* W1  = (const float*)d_in[5];
    const float* b1  = (const float*)d_in[6];
    const float* Wse = (const float*)d_in[7];
    const float* bse = (const float*)d_in[8];
    const float* W2  = (const float*)d_in[9];
    const float* b2  = (const float*)d_in[10];
    float* out = (float*)d_out;

    char* ws = (char*)d_ws;
    _Float16* W1T    = (_Float16*)ws;                          // 512 KB
    _Float16* WseH   = (_Float16*)(ws + (512 << 10));          // 512 KB
    float*    s_part = (float*)(ws + (1 << 20));               // BQ*2*128*4 = 512 KB
    float*    msum   = (float*)(ws + (1 << 20) + (512 << 10)); // BQ*512*4 = 1 MB

    prep_kernel<<<dim3(16, 17), 256, 0, stream>>>(W1, W1T, Wse, WseH);
    gemm_h_kernel<<<dim3(BQ, 2), 512, 0, stream>>>(qs1, ks, sg, W1T, b1, W2, s_part, msum);
    finish_kernel<<<dim3(BQ, 4), 256, 0, stream>>>(s_part, msum, sg, vs, WseH, bse, b2, out);
}

// Round 3
// 145.476 us; speedup vs baseline: 1.2047x; 1.1080x over previous
//
#include <hip/hip_runtime.h>
#include <stdint.h>
#include <stddef.h>

#define BDIM 4
#define QUE  128
#define VAL  128
#define DD   512
#define BQ   (BDIM*QUE)
#define BK   32
// swizzle: row r, true 8-f16 kseg c stored at slot cs = (c + SROW(r)) & 3
#define SROW(r) ((((r) + ((r) >> 2))) & 3)

typedef float    f32x4 __attribute__((ext_vector_type(4)));
typedef float    f32x2 __attribute__((ext_vector_type(2)));
typedef _Float16 f16x8 __attribute__((ext_vector_type(8)));
typedef _Float16 f16x4 __attribute__((ext_vector_type(4)));
typedef _Float16 f16x2 __attribute__((ext_vector_type(2)));

typedef const __attribute__((address_space(1))) void* gas_ptr;
typedef __attribute__((address_space(3))) void*       las_ptr;

__device__ __forceinline__ void async_copy16(const void* g, void* l) {
    __builtin_amdgcn_global_load_lds((gas_ptr)g, (las_ptr)l, 16, 0, 0);
}

// ---------------- prep: W1 transpose+cast to fp16 [e][d]; Wse cast to fp16 -------
__global__ __launch_bounds__(256) void prep_kernel(const float* __restrict__ W1,
                                                   _Float16* __restrict__ W1T,
                                                   const float* __restrict__ Wse,
                                                   _Float16* __restrict__ WseH) {
    if (blockIdx.y < 16) {
        __shared__ float tile[32][33];
        int tx = threadIdx.x & 31;
        int ty = threadIdx.x >> 5;            // 0..7
        int d0 = blockIdx.x * 32;
        int e0 = blockIdx.y * 32;
        #pragma unroll
        for (int r = 0; r < 4; ++r)
            tile[ty + r*8][tx] = W1[(size_t)(d0 + ty + r*8) * DD + e0 + tx];
        __syncthreads();
        #pragma unroll
        for (int r = 0; r < 4; ++r) {
            int el = ty + r*8;
            W1T[(size_t)(e0 + el) * DD + d0 + tx] = (_Float16)tile[tx][el];
        }
    } else {
        // cast Wse (262144 floats) -> fp16: 16 blocks x 256 threads x 16 iters x 4
        size_t base = (size_t)blockIdx.x * 16384 + threadIdx.x * 4;
        #pragma unroll 4
        for (int i = 0; i < 16; ++i) {
            f32x4 w = *(const f32x4*)(Wse + base + (size_t)i * 1024);
            f16x4 h;
            h[0] = (_Float16)w[0]; h[1] = (_Float16)w[1];
            h[2] = (_Float16)w[2]; h[3] = (_Float16)w[3];
            *(f16x4*)(WseH + base + (size_t)i * 1024) = h;
        }
    }
}

// ---------------- fused GEMM: h=relu((q*k)@W1+b1); emit s-partials + masked colsums
// grid (BQ, 2); block 512 = 8 waves as 2m x 4n of 64x64. Tile 128 rows x 256 e-cols.
// LDS rows are 64 B (BK=32 f16), kseg-swizzled; B staged by global_load_lds x2.
__global__ __launch_bounds__(512, 4) void gemm_h_kernel(
    const float* __restrict__ qs1,
    const float* __restrict__ ks,
    const int*   __restrict__ sgmask,
    const _Float16* __restrict__ W1T,   // [e][d] fp16
    const float* __restrict__ b1,
    const float* __restrict__ W2,
    float* __restrict__ s_part,         // [BQ][2][VAL]
    float* __restrict__ meansum)        // [BQ][DD]
{
    __shared__ _Float16 Ah[128 * BK];     // x tile   [v][k]
    __shared__ _Float16 Bh[256 * BK];     // W1T tile [e][k]
    __shared__ float qrow[DD];
    __shared__ float sred[4][VAL];
    __shared__ float msumLDS[2][256];

    const int tid  = threadIdx.x;
    const int bq   = blockIdx.x;
    const int gy   = blockIdx.y;          // e-half: cols [gy*256, gy*256+256)
    const int b    = bq >> 7;
    const int lane = tid & 63;
    const int wid  = tid >> 6;            // 0..7
    const int wm   = wid >> 2;            // 0..1 (rows wm*64)
    const int wn   = wid & 3;             // 0..3 (cols wn*64)
    const int quad = lane >> 4;
    const int lr   = lane & 15;

    if (tid < 128)
        *(f32x4*)(qrow + tid * 4) = *(const f32x4*)(qs1 + (size_t)bq * DD + tid * 4);

    f32x4 acc[4][4];
    #pragma unroll
    for (int i = 0; i < 4; ++i)
        #pragma unroll
        for (int j = 0; j < 4; ++j) acc[i][j] = (f32x4){0.f, 0.f, 0.f, 0.f};

    // ---- staging maps (fixed across K loop) ----
    const int r4 = tid >> 2;              // 0..127: A row / B local row
    const int cs = tid & 3;               // stored slot
    // A: this thread produces slot cs of row r4 -> true kseg ca
    const int ca = (cs - SROW(r4)) & 3;
    const float* ksrow = ks + ((size_t)b * VAL + r4) * DD + ca * 8;
    const float* qbase = qrow + ca * 8;
    _Float16* a_dst = &Ah[r4 * BK + cs * 8];
    // B: two async calls; call j covers rows j*128 + r4
    const int rb1 = 128 + r4;
    const int cb0 = (cs - SROW(r4)) & 3;
    const int cb1 = (cs - SROW(rb1)) & 3;
    const _Float16* gB0 = W1T + (size_t)(gy * 256 + r4) * DD + cb0 * 8;
    const _Float16* gB1 = W1T + (size_t)(gy * 256 + rb1) * DD + cb1 * 8;
    _Float16* ldsB0 = &Bh[(wid * 16) * BK];          // wave-uniform base, lane*16B
    _Float16* ldsB1 = &Bh[(128 + wid * 16) * BK];

    // ---- fragment LDS addresses (loop-invariant) ----
    const _Float16* fa_ptr[4];
    const _Float16* fb_ptr[4];
    #pragma unroll
    for (int mt = 0; mt < 4; ++mt) {
        int row = wm * 64 + mt * 16 + lr;
        fa_ptr[mt] = &Ah[row * BK + ((quad + SROW(row)) & 3) * 8];
    }
    #pragma unroll
    for (int nt = 0; nt < 4; ++nt) {
        int row = wn * 64 + nt * 16 + lr;
        fb_ptr[nt] = &Bh[row * BK + ((quad + SROW(row)) & 3) * 8];
    }
    __syncthreads();   // qrow ready

    for (int kk = 0; kk < DD; kk += BK) {
        // ---- B: async global->LDS (16 B/lane, swizzled source kseg)
        async_copy16(gB0 + kk, ldsB0);
        async_copy16(gB1 + kk, ldsB1);
        // ---- A: x = q*k, fp32->fp16 RNE, one b128 write
        f32x4 kv0 = *(const f32x4*)(ksrow + kk);
        f32x4 kv1 = *(const f32x4*)(ksrow + kk + 4);
        f32x4 qv0 = *(const f32x4*)(qbase + kk);
        f32x4 qv1 = *(const f32x4*)(qbase + kk + 4);
        f16x8 av;
        #pragma unroll
        for (int c = 0; c < 4; ++c) {
            av[c]     = (_Float16)(kv0[c] * qv0[c]);
            av[c + 4] = (_Float16)(kv1[c] * qv1[c]);
        }
        *(f16x8*)a_dst = av;
        __syncthreads();

        // ---- MFMA: A[m=lr][k=quad*8+j], B[k=quad*8+j][n=lr]
        f16x8 fa[4];
        #pragma unroll
        for (int mt = 0; mt < 4; ++mt) fa[mt] = *(const f16x8*)fa_ptr[mt];
        #pragma unroll
        for (int nt = 0; nt < 4; ++nt) {
            f16x8 fb = *(const f16x8*)fb_ptr[nt];
            #pragma unroll
            for (int mt = 0; mt < 4; ++mt)
                acc[mt][nt] = __builtin_amdgcn_mfma_f32_16x16x32_f16(fa[mt], fb, acc[mt][nt], 0, 0, 0);
        }
        __syncthreads();
    }

    // ---- fused epilogue: C/D layout col=lr (e), row=quad*4+reg (v)
    float b1v[4], w2v[4];
    #pragma unroll
    for (int nt = 0; nt < 4; ++nt) {
        int col = gy*256 + wn*64 + nt*16 + lr;
        b1v[nt] = b1[col];
        w2v[nt] = W2[col];
    }
    float msum[4] = {0.f, 0.f, 0.f, 0.f};
    #pragma unroll
    for (int mt = 0; mt < 4; ++mt) {
        #pragma unroll
        for (int reg = 0; reg < 4; ++reg) {
            int v = wm*64 + mt*16 + quad*4 + reg;
            int masked = sgmask[b * VAL + v];
            float sacc = 0.f;
            #pragma unroll
            for (int nt = 0; nt < 4; ++nt) {
                float h = acc[mt][nt][reg] + b1v[nt];
                h = fmaxf(h, 0.f);
                sacc += h * w2v[nt];
                if (!masked) msum[nt] += h;
            }
            sacc += __shfl_xor(sacc, 1);
            sacc += __shfl_xor(sacc, 2);
            sacc += __shfl_xor(sacc, 4);
            sacc += __shfl_xor(sacc, 8);
            if (lr == 0) sred[wn][v] = sacc;
        }
    }
    #pragma unroll
    for (int nt = 0; nt < 4; ++nt) {
        float m = msum[nt];
        m += __shfl_xor(m, 16);
        m += __shfl_xor(m, 32);
        if (lane < 16) msumLDS[wm][wn*64 + nt*16 + lr] = m;
    }
    __syncthreads();
    if (tid < 128) {
        s_part[((size_t)bq * 2 + gy) * VAL + tid] =
            sred[0][tid] + sred[1][tid] + sred[2][tid] + sred[3][tid];
    } else if (tid >= 256) {
        int c = tid - 256;
        meansum[(size_t)bq * DD + gy*256 + c] = msumLDS[0][c] + msumLDS[1][c];
    }
}

// ---------------- finish: softmax, gate, weighted sum — grid (BQ, 4 d-tiles) ------
// 256 threads: (tid&63) = d-pair, (tid>>6) = e/v quarter. 2 d per thread.
__global__ __launch_bounds__(256) void finish_kernel(
    const float* __restrict__ s_part,     // [BQ][2][VAL]
    const float* __restrict__ meansum,    // [BQ][DD] (un-normalized)
    const int*   __restrict__ sgmask,
    const float* __restrict__ vs,
    const _Float16* __restrict__ WseH,    // [e][d] fp16
    const float* __restrict__ bse,
    const float* __restrict__ b2,
    float* __restrict__ out)
{
    __shared__ float wexp[VAL];
    __shared__ float meanLDS[DD];         // raw colsums (1/denom deferred — linear)
    __shared__ float gred[4][128];
    __shared__ float ored[4][128];
    __shared__ float redv[2];             // [0]=1/sum_exp  [1]=1/denom
    const int tid = threadIdx.x;
    const int bq  = blockIdx.x;
    const int dt  = blockIdx.y;
    const int b   = bq >> 7;

    meanLDS[tid]       = meansum[(size_t)bq * DD + tid];
    meanLDS[tid + 256] = meansum[(size_t)bq * DD + tid + 256];

    if (tid < 64) {   // wave 0: softmax over 128 v (2/lane) + denom count
        int v0 = tid, v1 = tid + 64;
        const float* sp = s_part + (size_t)bq * 2 * VAL;
        float s0 = fmaxf(sp[v0] + sp[VAL + v0] + b2[0], 0.f);
        float s1 = fmaxf(sp[v1] + sp[VAL + v1] + b2[0], 0.f);
        int m0 = sgmask[b * VAL + v0], m1 = sgmask[b * VAL + v1];
        float cnt = (m0 ? 0.f : 1.f) + (m1 ? 0.f : 1.f);
        if (m0) s0 = -1e9f;
        if (m1) s1 = -1e9f;
        float mx = fmaxf(s0, s1);
        #pragma unroll
        for (int off = 32; off; off >>= 1) mx = fmaxf(mx, __shfl_xor(mx, off));
        float e0 = __expf(s0 - mx), e1 = __expf(s1 - mx);
        float se = e0 + e1;
        #pragma unroll
        for (int off = 32; off; off >>= 1) {
            se  += __shfl_xor(se, off);
            cnt += __shfl_xor(cnt, off);
        }
        wexp[v0] = e0;  wexp[v1] = e1;
        if (tid == 0) { redv[0] = 1.f / se; redv[1] = 1.f / cnt; }
    }
    __syncthreads();

    const int dp = tid & 63;              // d-pair index
    const int q4 = tid >> 6;              // quarter (wave-uniform)
    const int d0 = dt * 128 + dp * 2;

    float g0 = 0.f, g1 = 0.f;
    const _Float16* wp = WseH + (size_t)(q4 * 128) * DD + d0;
    const float*    mp = meanLDS + q4 * 128;
    #pragma unroll 8
    for (int e = 0; e < 128; ++e) {
        f16x2 w = *(const f16x2*)(wp + (size_t)e * DD);
        float m = mp[e];
        g0 += m * (float)w[0];
        g1 += m * (float)w[1];
    }
    *(f32x2*)&gred[q4][dp * 2] = (f32x2){g0, g1};

    float o0 = 0.f, o1 = 0.f;
    const float* vp = vs + ((size_t)b * VAL + q4 * 32) * DD + d0;
    const float* wx = wexp + q4 * 32;
    #pragma unroll 8
    for (int v = 0; v < 32; ++v) {
        f32x2 vv = *(const f32x2*)(vp + (size_t)v * DD);
        o0 += wx[v] * vv[0];
        o1 += wx[v] * vv[1];
    }
    *(f32x2*)&ored[q4][dp * 2] = (f32x2){o0, o1};
    __syncthreads();

    if (tid < 128) {
        int d = dt * 128 + tid;
        float gate = (gred[0][tid] + gred[1][tid] + gred[2][tid] + gred[3][tid]) * redv[1] + bse[d];
        gate = fmaxf(gate, 0.f);
        gate = 1.f / (1.f + __expf(-gate));
        float o = ored[0][tid] + ored[1][tid] + ored[2][tid] + ored[3][tid];
        out[(size_t)bq * DD + d] = gate * o * redv[0];
    }
}

extern "C" void kernel_launch(void* const* d_in, const int* in_sizes, int n_in,
                              void* d_out, int out_size, void* d_ws, size_t ws_size,
                              hipStream_t stream) {
    (void)in_sizes; (void)n_in; (void)out_size; (void)ws_size;
    const float* qs1 = (const float*)d_in[0];
    const float* ks  = (const float*)d_in[2];
    const float* vs  = (const float*)d_in[3];
    const int*   sg  = (const int*)d_in[4];
    const float* W1  = (const float*)d_in[5];
    const float* b1  = (const float*)d_in[6];
    const float* Wse = (const float*)d_in[7];
    const float* bse = (const float*)d_in[8];
    const float* W2  = (const float*)d_in[9];
    const float* b2  = (const float*)d_in[10];
    float* out = (float*)d_out;

    char* ws = (char*)d_ws;
    _Float16* W1T    = (_Float16*)ws;                          // 512 KB
    _Float16* WseH   = (_Float16*)(ws + (512 << 10));          // 512 KB
    float*    s_part = (float*)(ws + (1 << 20));               // 512 KB
    float*    msum   = (float*)(ws + (1 << 20) + (512 << 10)); // 1 MB

    prep_kernel<<<dim3(16, 17), 256, 0, stream>>>(W1, W1T, Wse, WseH);
    gemm_h_kernel<<<dim3(BQ, 2), 512, 0, stream>>>(qs1, ks, sg, W1T, b1, W2, s_part, msum);
    finish_kernel<<<dim3(BQ, 4), 256, 0, stream>>>(s_part, msum, sg, vs, WseH, bse, b2, out);
}

// Round 4
// 139.203 us; speedup vs baseline: 1.2590x; 1.0451x over previous
//
#include <hip/hip_runtime.h>
#include <stdint.h>
#include <stddef.h>

#define BDIM 4
#define QUE  128
#define VAL  128
#define DD   512
#define BQ   (BDIM*QUE)
#define BK   32
// swizzle: row r, true 8-f16 kseg c stored at slot cs = (c + SROW(r)) & 3
#define SROW(r) ((((r) + ((r) >> 2))) & 3)

typedef float    f32x4 __attribute__((ext_vector_type(4)));
typedef float    f32x2 __attribute__((ext_vector_type(2)));
typedef _Float16 f16x8 __attribute__((ext_vector_type(8)));
typedef _Float16 f16x4 __attribute__((ext_vector_type(4)));
typedef _Float16 f16x2 __attribute__((ext_vector_type(2)));

typedef const __attribute__((address_space(1))) void* gas_ptr;
typedef __attribute__((address_space(3))) void*       las_ptr;

__device__ __forceinline__ void async_copy16(const void* g, void* l) {
    __builtin_amdgcn_global_load_lds((gas_ptr)g, (las_ptr)l, 16, 0, 0);
}

// ---------------- prep: fp16 transposes  W1->W1T[e][d], Wse->WseT[d][e],
//                  vs->vsT[b][d][v] -------------------------------------------
__global__ __launch_bounds__(256) void prep_kernel(const float* __restrict__ W1,
                                                   _Float16* __restrict__ W1T,
                                                   const float* __restrict__ Wse,
                                                   _Float16* __restrict__ WseT,
                                                   const float* __restrict__ vs,
                                                   _Float16* __restrict__ vsT) {
    __shared__ float tile[32][33];
    const int tx = threadIdx.x & 31;
    const int ty = threadIdx.x >> 5;      // 0..7
    const int gx = blockIdx.x, gy = blockIdx.y;
    if (gy < 32) {
        const float* src = (gy < 16) ? W1  : Wse;
        _Float16*    dst = (gy < 16) ? W1T : WseT;
        int a0 = gx * 32;                 // source-row tile
        int b0 = (gy & 15) * 32;          // source-col tile
        #pragma unroll
        for (int r = 0; r < 4; ++r)
            tile[ty + r*8][tx] = src[(size_t)(a0 + ty + r*8) * DD + b0 + tx];
        __syncthreads();
        #pragma unroll
        for (int r = 0; r < 4; ++r) {
            int el = ty + r*8;
            dst[(size_t)(b0 + el) * DD + a0 + tx] = (_Float16)tile[tx][el];
        }
    } else {
        // vs[b][v][d] -> vsT[b][d][v], b = gy-32, d-tile = gx
        int bb = gy - 32;
        const float* src = vs  + (size_t)bb * VAL * DD;
        _Float16*    dst = vsT + (size_t)bb * DD * VAL;
        int b0 = gx * 32;                 // d tile
        for (int vt = 0; vt < 4; ++vt) {
            int a0 = vt * 32;             // v tile
            __syncthreads();
            #pragma unroll
            for (int r = 0; r < 4; ++r)
                tile[ty + r*8][tx] = src[(size_t)(a0 + ty + r*8) * DD + b0 + tx];
            __syncthreads();
            #pragma unroll
            for (int r = 0; r < 4; ++r) {
                int el = ty + r*8;
                dst[(size_t)(b0 + el) * VAL + a0 + tx] = (_Float16)tile[tx][el];
            }
        }
    }
}

// ---------------- fused GEMM: h=relu((q*k)@W1+b1); emit s-partials + masked colsums
// grid (BQ, 2); block 512 = 8 waves as 2m x 4n of 64x64. Tile 128 rows x 256 e-cols.
__global__ __launch_bounds__(512, 4) void gemm_h_kernel(
    const float* __restrict__ qs1,
    const float* __restrict__ ks,
    const int*   __restrict__ sgmask,
    const _Float16* __restrict__ W1T,   // [e][d] fp16
    const float* __restrict__ b1,
    const float* __restrict__ W2,
    float* __restrict__ s_part,         // [BQ][2][VAL]
    float* __restrict__ meansum)        // [BQ][DD]
{
    __shared__ _Float16 Ah[128 * BK];     // x tile   [v][k]
    __shared__ _Float16 Bh[256 * BK];     // W1T tile [e][k]
    __shared__ float qrow[DD];
    __shared__ float sred[4][VAL];
    __shared__ float msumLDS[2][256];

    const int tid  = threadIdx.x;
    const int bq   = blockIdx.x;
    const int gy   = blockIdx.y;          // e-half: cols [gy*256, gy*256+256)
    const int b    = bq >> 7;
    const int lane = tid & 63;
    const int wid  = tid >> 6;            // 0..7
    const int wm   = wid >> 2;            // 0..1 (rows wm*64)
    const int wn   = wid & 3;             // 0..3 (cols wn*64)
    const int quad = lane >> 4;
    const int lr   = lane & 15;

    if (tid < 128)
        *(f32x4*)(qrow + tid * 4) = *(const f32x4*)(qs1 + (size_t)bq * DD + tid * 4);

    f32x4 acc[4][4];
    #pragma unroll
    for (int i = 0; i < 4; ++i)
        #pragma unroll
        for (int j = 0; j < 4; ++j) acc[i][j] = (f32x4){0.f, 0.f, 0.f, 0.f};

    // ---- staging maps ----
    const int r4 = tid >> 2;              // 0..127
    const int cs = tid & 3;               // stored slot
    const int ca = (cs - SROW(r4)) & 3;
    const float* ksrow = ks + ((size_t)b * VAL + r4) * DD + ca * 8;
    const float* qbase = qrow + ca * 8;
    _Float16* a_dst = &Ah[r4 * BK + cs * 8];
    const int rb1 = 128 + r4;
    const int cb1 = (cs - SROW(rb1)) & 3;
    const _Float16* gB0 = W1T + (size_t)(gy * 256 + r4) * DD + ca * 8;
    const _Float16* gB1 = W1T + (size_t)(gy * 256 + rb1) * DD + cb1 * 8;
    _Float16* ldsB0 = &Bh[(wid * 16) * BK];          // wave-uniform base, lane*16B
    _Float16* ldsB1 = &Bh[(128 + wid * 16) * BK];

    // ---- fragment LDS addresses (loop-invariant) ----
    const _Float16* fa_ptr[4];
    const _Float16* fb_ptr[4];
    #pragma unroll
    for (int mt = 0; mt < 4; ++mt) {
        int row = wm * 64 + mt * 16 + lr;
        fa_ptr[mt] = &Ah[row * BK + ((quad + SROW(row)) & 3) * 8];
    }
    #pragma unroll
    for (int nt = 0; nt < 4; ++nt) {
        int row = wn * 64 + nt * 16 + lr;
        fb_ptr[nt] = &Bh[row * BK + ((quad + SROW(row)) & 3) * 8];
    }
    __syncthreads();   // qrow ready

    for (int kk = 0; kk < DD; kk += BK) {
        async_copy16(gB0 + kk, ldsB0);
        async_copy16(gB1 + kk, ldsB1);
        f32x4 kv0 = *(const f32x4*)(ksrow + kk);
        f32x4 kv1 = *(const f32x4*)(ksrow + kk + 4);
        f32x4 qv0 = *(const f32x4*)(qbase + kk);
        f32x4 qv1 = *(const f32x4*)(qbase + kk + 4);
        f16x8 av;
        #pragma unroll
        for (int c = 0; c < 4; ++c) {
            av[c]     = (_Float16)(kv0[c] * qv0[c]);
            av[c + 4] = (_Float16)(kv1[c] * qv1[c]);
        }
        *(f16x8*)a_dst = av;
        __syncthreads();

        f16x8 fa[4];
        #pragma unroll
        for (int mt = 0; mt < 4; ++mt) fa[mt] = *(const f16x8*)fa_ptr[mt];
        #pragma unroll
        for (int nt = 0; nt < 4; ++nt) {
            f16x8 fb = *(const f16x8*)fb_ptr[nt];
            #pragma unroll
            for (int mt = 0; mt < 4; ++mt)
                acc[mt][nt] = __builtin_amdgcn_mfma_f32_16x16x32_f16(fa[mt], fb, acc[mt][nt], 0, 0, 0);
        }
        __syncthreads();
    }

    // ---- fused epilogue: C/D layout col=lr (e), row=quad*4+reg (v)
    float b1v[4], w2v[4];
    #pragma unroll
    for (int nt = 0; nt < 4; ++nt) {
        int col = gy*256 + wn*64 + nt*16 + lr;
        b1v[nt] = b1[col];
        w2v[nt] = W2[col];
    }
    float msum[4] = {0.f, 0.f, 0.f, 0.f};
    #pragma unroll
    for (int mt = 0; mt < 4; ++mt) {
        #pragma unroll
        for (int reg = 0; reg < 4; ++reg) {
            int v = wm*64 + mt*16 + quad*4 + reg;
            int masked = sgmask[b * VAL + v];
            float sacc = 0.f;
            #pragma unroll
            for (int nt = 0; nt < 4; ++nt) {
                float h = acc[mt][nt][reg] + b1v[nt];
                h = fmaxf(h, 0.f);
                sacc += h * w2v[nt];
                if (!masked) msum[nt] += h;
            }
            sacc += __shfl_xor(sacc, 1);
            sacc += __shfl_xor(sacc, 2);
            sacc += __shfl_xor(sacc, 4);
            sacc += __shfl_xor(sacc, 8);
            if (lr == 0) sred[wn][v] = sacc;
        }
    }
    #pragma unroll
    for (int nt = 0; nt < 4; ++nt) {
        float m = msum[nt];
        m += __shfl_xor(m, 16);
        m += __shfl_xor(m, 32);
        if (lane < 16) msumLDS[wm][wn*64 + nt*16 + lr] = m;
    }
    __syncthreads();
    if (tid < 128) {
        s_part[((size_t)bq * 2 + gy) * VAL + tid] =
            sred[0][tid] + sred[1][tid] + sred[2][tid] + sred[3][tid];
    } else if (tid >= 256) {
        int c = tid - 256;
        meansum[(size_t)bq * DD + gy*256 + c] = msumLDS[0][c] + msumLDS[1][c];
    }
}

// ---------------- mid: per-bq masked softmax -> wH (1/se folded), meanH (1/denom)
__global__ __launch_bounds__(64) void mid_kernel(
    const float* __restrict__ s_part,     // [BQ][2][VAL]
    const float* __restrict__ meansum,    // [BQ][DD]
    const int*   __restrict__ sgmask,
    const float* __restrict__ b2,
    _Float16* __restrict__ wH,            // [BQ][VAL]
    _Float16* __restrict__ meanH)         // [BQ][DD]
{
    const int bq = blockIdx.x;
    const int b  = bq >> 7;
    const int lane = threadIdx.x;
    const float* sp = s_part + (size_t)bq * 2 * VAL;
    float s0 = fmaxf(sp[lane]      + sp[128 + lane]      + b2[0], 0.f);
    float s1 = fmaxf(sp[64 + lane] + sp[192 + lane]      + b2[0], 0.f);
    int m0 = sgmask[b * VAL + lane], m1 = sgmask[b * VAL + 64 + lane];
    float cnt = (m0 ? 0.f : 1.f) + (m1 ? 0.f : 1.f);
    if (m0) s0 = -1e9f;
    if (m1) s1 = -1e9f;
    float mx = fmaxf(s0, s1);
    #pragma unroll
    for (int off = 32; off; off >>= 1) mx = fmaxf(mx, __shfl_xor(mx, off));
    float e0 = __expf(s0 - mx), e1 = __expf(s1 - mx);
    float se = e0 + e1;
    #pragma unroll
    for (int off = 32; off; off >>= 1) {
        se  += __shfl_xor(se, off);
        cnt += __shfl_xor(cnt, off);
    }
    float invse = 1.f / se;
    float invd  = 1.f / cnt;
    f16x2 wv; wv[0] = (_Float16)(e0 * invse); wv[1] = (_Float16)(e1 * invse);
    wH[(size_t)bq * VAL + lane]      = wv[0];
    wH[(size_t)bq * VAL + 64 + lane] = wv[1];
    // meanH: 8 elems per lane
    f32x4 mA = *(const f32x4*)(meansum + (size_t)bq * DD + lane * 8);
    f32x4 mB = *(const f32x4*)(meansum + (size_t)bq * DD + lane * 8 + 4);
    f16x8 mh;
    #pragma unroll
    for (int c = 0; c < 4; ++c) {
        mh[c]     = (_Float16)(mA[c] * invd);
        mh[c + 4] = (_Float16)(mB[c] * invd);
    }
    *(f16x8*)(meanH + (size_t)bq * DD + lane * 8) = mh;
}

// ---------------- final: gate = sigmoid(relu(meanH@WseT + bse)); out = gate*(wH@vsT)
// grid (16 q-tiles of 32, 8 d-tiles of 64), 1 wave. Direct-from-global MFMA frags.
__global__ __launch_bounds__(64) void final_kernel(
    const _Float16* __restrict__ meanH,   // [BQ][DD]
    const _Float16* __restrict__ WseT,    // [d][e] fp16
    const _Float16* __restrict__ wH,      // [BQ][VAL]
    const _Float16* __restrict__ vsT,     // [b][d][v] fp16
    const float* __restrict__ bse,
    float* __restrict__ out)              // [BQ][DD]
{
    const int lane = threadIdx.x;
    const int lr   = lane & 15;
    const int quad = lane >> 4;
    const int q0   = blockIdx.x * 32;
    const int d0   = blockIdx.y * 64;
    const int b    = q0 >> 7;

    f32x4 ga[2][4], oa[2][4];
    #pragma unroll
    for (int i = 0; i < 2; ++i)
        #pragma unroll
        for (int j = 0; j < 4; ++j) { ga[i][j] = (f32x4){0,0,0,0}; oa[i][j] = (f32x4){0,0,0,0}; }

    // gate GEMM: K = 512 (e)
    const _Float16* ap0 = meanH + (size_t)(q0 + lr) * DD + quad * 8;
    const _Float16* bp0 = WseT  + (size_t)(d0 + lr) * DD + quad * 8;
    #pragma unroll 2
    for (int kk = 0; kk < DD; kk += 32) {
        f16x8 am[2];
        #pragma unroll
        for (int mt = 0; mt < 2; ++mt)
            am[mt] = *(const f16x8*)(ap0 + (size_t)mt * 16 * DD + kk);
        #pragma unroll
        for (int nt = 0; nt < 4; ++nt) {
            f16x8 bw = *(const f16x8*)(bp0 + (size_t)nt * 16 * DD + kk);
            #pragma unroll
            for (int mt = 0; mt < 2; ++mt)
                ga[mt][nt] = __builtin_amdgcn_mfma_f32_16x16x32_f16(am[mt], bw, ga[mt][nt], 0, 0, 0);
        }
    }
    // out GEMM: K = 128 (v)
    const _Float16* wp0 = wH  + (size_t)(q0 + lr) * VAL + quad * 8;
    const _Float16* vp0 = vsT + (size_t)b * DD * VAL + (size_t)(d0 + lr) * VAL + quad * 8;
    #pragma unroll
    for (int kk = 0; kk < VAL; kk += 32) {
        f16x8 am[2];
        #pragma unroll
        for (int mt = 0; mt < 2; ++mt)
            am[mt] = *(const f16x8*)(wp0 + (size_t)mt * 16 * VAL + kk);
        #pragma unroll
        for (int nt = 0; nt < 4; ++nt) {
            f16x8 bv = *(const f16x8*)(vp0 + (size_t)nt * 16 * VAL + kk);
            #pragma unroll
            for (int mt = 0; mt < 2; ++mt)
                oa[mt][nt] = __builtin_amdgcn_mfma_f32_16x16x32_f16(am[mt], bv, oa[mt][nt], 0, 0, 0);
        }
    }
    // epilogue: C/D col=lr, row=quad*4+reg
    #pragma unroll
    for (int nt = 0; nt < 4; ++nt) {
        int col = d0 + nt * 16 + lr;
        float bsev = bse[col];
        #pragma unroll
        for (int mt = 0; mt < 2; ++mt) {
            #pragma unroll
            for (int reg = 0; reg < 4; ++reg) {
                int row = q0 + mt * 16 + quad * 4 + reg;
                float garg = ga[mt][nt][reg] + bsev;
                garg = fmaxf(garg, 0.f);
                float gate = 1.f / (1.f + __expf(-garg));
                out[(size_t)row * DD + col] = gate * oa[mt][nt][reg];
            }
        }
    }
}

extern "C" void kernel_launch(void* const* d_in, const int* in_sizes, int n_in,
                              void* d_out, int out_size, void* d_ws, size_t ws_size,
                              hipStream_t stream) {
    (void)in_sizes; (void)n_in; (void)out_size; (void)ws_size;
    const float* qs1 = (const float*)d_in[0];
    const float* ks  = (const float*)d_in[2];
    const float* vs  = (const float*)d_in[3];
    const int*   sg  = (const int*)d_in[4];
    const float* W1  = (const float*)d_in[5];
    const float* b1  = (const float*)d_in[6];
    const float* Wse = (const float*)d_in[7];
    const float* bse = (const float*)d_in[8];
    const float* W2  = (const float*)d_in[9];
    const float* b2  = (const float*)d_in[10];
    float* out = (float*)d_out;

    char* ws = (char*)d_ws;
    _Float16* W1T    = (_Float16*)(ws);                        // 512 KB
    _Float16* WseT   = (_Float16*)(ws + (512 << 10));          // 512 KB
    _Float16* vsT    = (_Float16*)(ws + (1 << 20));            // 512 KB
    float*    s_part = (float*)(ws + (1536 << 10));            // 512 KB
    float*    msum   = (float*)(ws + (2 << 20));               // 1 MB
    _Float16* wH     = (_Float16*)(ws + (3 << 20));            // 128 KB
    _Float16* meanH  = (_Float16*)(ws + (3 << 20) + (128 << 10)); // 512 KB

    prep_kernel<<<dim3(16, 36), 256, 0, stream>>>(W1, W1T, Wse, WseT, vs, vsT);
    gemm_h_kernel<<<dim3(BQ, 2), 512, 0, stream>>>(qs1, ks, sg, W1T, b1, W2, s_part, msum);
    mid_kernel<<<BQ, 64, 0, stream>>>(s_part, msum, sg, b2, wH, meanH);
    final_kernel<<<dim3(16, 8), 64, 0, stream>>>(meanH, WseT, wH, vsT, bse, out);
}